// Round 5
// baseline (699.753 us; speedup 1.0000x reference)
//
#include <hip/hip_runtime.h>
#include <stdint.h>
#include <stddef.h>

typedef __bf16 bf16x8 __attribute__((ext_vector_type(8)));
typedef short short8 __attribute__((ext_vector_type(8)));
typedef float floatx4 __attribute__((ext_vector_type(4)));
typedef float f32x16 __attribute__((ext_vector_type(16)));
typedef unsigned short ushort4v __attribute__((ext_vector_type(4)));
typedef unsigned int uint2v __attribute__((ext_vector_type(2)));

__device__ __forceinline__ unsigned short f2bf(float f){
  unsigned int u = __float_as_uint(f);
  u += 0x7fffu + ((u >> 16) & 1u);
  return (unsigned short)(u >> 16);
}
__device__ __forceinline__ float bf2f(unsigned short s){
  return __uint_as_float(((unsigned int)s) << 16);
}
__device__ __forceinline__ void gl2lds16(const void* g, void* l){
  __builtin_amdgcn_global_load_lds((const __attribute__((address_space(1))) void*)g,
                                   (__attribute__((address_space(3))) void*)l, 16, 0, 0);
}

// ---------------- fp32 -> bf16 flat convert (n multiple of 1024) ----------------
__global__ __launch_bounds__(256) void conv_f32_bf16(const float* __restrict__ in,
                                                     unsigned short* __restrict__ out){
  int t = blockIdx.x * 256 + threadIdx.x;
  floatx4 v = *(const floatx4*)(in + (size_t)t * 4);
  ushort4v o;
#pragma unroll
  for (int j = 0; j < 4; ++j) o[j] = f2bf(v[j]);
  *(ushort4v*)(out + (size_t)t * 4) = o;
}

// ---------------- transpose+convert: fp32 [Kd,Nd] -> bf16 [Nd,Kd] ----------------
__global__ __launch_bounds__(256) void transpose_cvt(const float* __restrict__ in,
                                                     unsigned short* __restrict__ out,
                                                     int Kd, int Nd){
  __shared__ __align__(16) unsigned short tile[64 * 80];
  int n0 = blockIdx.x * 64, k0 = blockIdx.y * 64;
  int t = threadIdx.x;
#pragma unroll
  for (int it = 0; it < 2; ++it){
    int rr = (t >> 3) + it * 32;
    int cc = t & 7;
    const float* src = in + (size_t)(k0 + rr) * Nd + n0 + cc * 8;
    floatx4 a = *(const floatx4*)src;
    floatx4 b = *(const floatx4*)(src + 4);
    short8 s;
#pragma unroll
    for (int j = 0; j < 4; ++j){ s[j] = (short)f2bf(a[j]); s[j + 4] = (short)f2bf(b[j]); }
    *(short8*)&tile[rr * 80 + cc * 8] = s;
  }
  __syncthreads();
#pragma unroll
  for (int it = 0; it < 2; ++it){
    int nr = (t >> 3) + it * 32;
    int kc = t & 7;
    short8 v;
#pragma unroll
    for (int j = 0; j < 8; ++j) v[j] = (short)tile[(kc * 8 + j) * 80 + nr];
    *(short8*)(out + (size_t)(n0 + nr) * Kd + k0 + kc * 8) = v;
  }
}

// ---------------- GEMM 256x256, BK=64, 8 waves, 4-phase counted-vmcnt schedule ------
// C[M,n] = A[M,4096] * Wt^T, Wt given as [N,4096] bf16.
// Region by n0: [0,4096) -> oQ bf16 (ld 4096) or oF fp32 if f32out; [4096,5120) -> oK;
// [5120,6144) -> oVt transposed.
// Schedule per K-tile t (computing from buf c=t&1, staging tile t+1 into c^1):
//   p0: read A-frags(ah0)+B-frags(bh0) | stage A0' | MFMA q(0,0) | vmcnt(4) | barrier
//   p1: read B-frags(bh1)              | stage B0' | MFMA q(0,1) | vmcnt(4) | barrier
//   p2: read A-frags(ah1)              | stage B1' | MFMA q(1,1) |          | barrier
//   p3: re-read B-frags(bh0)           | stage A1' | MFMA q(1,0) | vmcnt(4) | barrier
// Ledger (2 loads/phase/thread): each vmcnt(4) leaves exactly the 2 youngest halves
// in flight; every half completes >=3 phases before its first ds_read. Tail keeps the
// ledger uniform by dummy-staging tile 63 into the dead buffer.
__global__ __launch_bounds__(512, 2) void gemm_bt(
    const unsigned short* __restrict__ A,
    const unsigned short* __restrict__ Wq,
    const unsigned short* __restrict__ Wk,
    const unsigned short* __restrict__ Wv,
    unsigned short* __restrict__ oQ,
    unsigned short* __restrict__ oK,
    unsigned short* __restrict__ oVt,
    float* __restrict__ oF, int f32out)
{
  __shared__ __align__(16) unsigned short As[2][256 * 64];  // 64 KB
  __shared__ __align__(16) unsigned short Bs[2][256 * 64];  // 64 KB
  const int tid = threadIdx.x;
  const int w = tid >> 6, lane = tid & 63, quad = lane >> 4, l15 = lane & 15;
  const int wr = w >> 2, wc = w & 3;      // wave grid 2(M) x 4(N)
  const int m0 = blockIdx.y * 256;
  const int n0 = blockIdx.x * 256;

  const unsigned short* Wsrc;
  int nb, region;
  if (n0 < 4096)      { Wsrc = Wq; nb = n0;        region = 0; }
  else if (n0 < 5120) { Wsrc = Wk; nb = n0 - 4096; region = 1; }
  else                { Wsrc = Wv; nb = n0 - 5120; region = 2; }

  floatx4 acc[8][4];
#pragma unroll
  for (int i = 0; i < 8; ++i)
#pragma unroll
    for (int j = 0; j < 4; ++j) acc[i][j] = (floatx4){0.f, 0.f, 0.f, 0.f};

  // Stage one 128-row half H of a 256x64 bf16 tile: linear LDS dest,
  // pre-swizzled global source (read side applies the same 16B-chunk XOR).
#define STG(SRC, ROW0, H, DST, K0)                                                     \
  { _Pragma("unroll")                                                                  \
    for (int rep_ = 0; rep_ < 2; ++rep_){                                              \
      int u_ = tid + rep_ * 512;                                                       \
      int r_ = (H) * 128 + (u_ >> 3);                                                  \
      int c_ = u_ & 7;                                                                 \
      gl2lds16((SRC) + ((size_t)((ROW0) + r_) << 12) + (K0) + ((c_ ^ (r_ & 7)) << 3),  \
               (char*)(DST) + (H) * 16384 + (size_t)u_ * 16);                          \
    } }

  // prologue: tile 0 -> buf 0, order A0,B0,B1,A1
  STG(A,    m0, 0, &As[0][0], 0);
  STG(Wsrc, nb, 0, &Bs[0][0], 0);
  STG(Wsrc, nb, 1, &Bs[0][0], 0);
  STG(A,    m0, 1, &As[0][0], 0);
  asm volatile("s_waitcnt vmcnt(4)" ::: "memory");   // A0,B0 of tile 0 complete
  __builtin_amdgcn_s_barrier();

  for (int t = 0; t < 64; ++t){
    const int cb = t & 1, nbuf = cb ^ 1;
    const int s = (t < 63) ? (t + 1) : 63;           // dummy-stage at the tail
    const int kn = s << 6;
    const unsigned short* Ac = &As[cb][0];
    const unsigned short* Bc = &Bs[cb][0];

    bf16x8 af[4][2], bf0[2][2], bf1[2][2];

    // ---------- phase 0: quadrant (ah0, bh0) ----------
#pragma unroll
    for (int i = 0; i < 4; ++i){
      int r = (wr * 4 + i) * 16 + l15;
#pragma unroll
      for (int ks = 0; ks < 2; ++ks){
        int kc = ks * 4 + quad;
        af[i][ks] = *(const bf16x8*)&Ac[r * 64 + ((kc ^ (r & 7)) << 3)];
      }
    }
#pragma unroll
    for (int j = 0; j < 2; ++j){
      int r = (wc * 2 + j) * 16 + l15;
#pragma unroll
      for (int ks = 0; ks < 2; ++ks){
        int kc = ks * 4 + quad;
        bf0[j][ks] = *(const bf16x8*)&Bc[r * 64 + ((kc ^ (r & 7)) << 3)];
      }
    }
    STG(A, m0, 0, &As[nbuf][0], kn);
    __builtin_amdgcn_s_setprio(1);
#pragma unroll
    for (int i = 0; i < 4; ++i)
#pragma unroll
      for (int j = 0; j < 2; ++j)
#pragma unroll
        for (int ks = 0; ks < 2; ++ks)
          acc[i][j] = __builtin_amdgcn_mfma_f32_16x16x32_bf16(af[i][ks], bf0[j][ks], acc[i][j], 0, 0, 0);
    __builtin_amdgcn_s_setprio(0);
    asm volatile("s_waitcnt vmcnt(4)" ::: "memory");
    __builtin_amdgcn_s_barrier();

    // ---------- phase 1: quadrant (ah0, bh1) ----------
#pragma unroll
    for (int j = 0; j < 2; ++j){
      int r = (8 + wc * 2 + j) * 16 + l15;
#pragma unroll
      for (int ks = 0; ks < 2; ++ks){
        int kc = ks * 4 + quad;
        bf1[j][ks] = *(const bf16x8*)&Bc[r * 64 + ((kc ^ (r & 7)) << 3)];
      }
    }
    STG(Wsrc, nb, 0, &Bs[nbuf][0], kn);
    __builtin_amdgcn_s_setprio(1);
#pragma unroll
    for (int i = 0; i < 4; ++i)
#pragma unroll
      for (int j = 0; j < 2; ++j)
#pragma unroll
        for (int ks = 0; ks < 2; ++ks)
          acc[i][2 + j] = __builtin_amdgcn_mfma_f32_16x16x32_bf16(af[i][ks], bf1[j][ks], acc[i][2 + j], 0, 0, 0);
    __builtin_amdgcn_s_setprio(0);
    asm volatile("s_waitcnt vmcnt(4)" ::: "memory");
    __builtin_amdgcn_s_barrier();

    // ---------- phase 2: quadrant (ah1, bh1) ----------
#pragma unroll
    for (int i = 0; i < 4; ++i){
      int r = (8 + wr * 4 + i) * 16 + l15;
#pragma unroll
      for (int ks = 0; ks < 2; ++ks){
        int kc = ks * 4 + quad;
        af[i][ks] = *(const bf16x8*)&Ac[r * 64 + ((kc ^ (r & 7)) << 3)];
      }
    }
    STG(Wsrc, nb, 1, &Bs[nbuf][0], kn);
    __builtin_amdgcn_s_setprio(1);
#pragma unroll
    for (int i = 0; i < 4; ++i)
#pragma unroll
      for (int j = 0; j < 2; ++j)
#pragma unroll
        for (int ks = 0; ks < 2; ++ks)
          acc[4 + i][2 + j] = __builtin_amdgcn_mfma_f32_16x16x32_bf16(af[i][ks], bf1[j][ks], acc[4 + i][2 + j], 0, 0, 0);
    __builtin_amdgcn_s_setprio(0);
    __builtin_amdgcn_s_barrier();

    // ---------- phase 3: quadrant (ah1, bh0) ----------
#pragma unroll
    for (int j = 0; j < 2; ++j){
      int r = (wc * 2 + j) * 16 + l15;
#pragma unroll
      for (int ks = 0; ks < 2; ++ks){
        int kc = ks * 4 + quad;
        bf0[j][ks] = *(const bf16x8*)&Bc[r * 64 + ((kc ^ (r & 7)) << 3)];
      }
    }
    STG(A, m0, 1, &As[nbuf][0], kn);
    __builtin_amdgcn_s_setprio(1);
#pragma unroll
    for (int i = 0; i < 4; ++i)
#pragma unroll
      for (int j = 0; j < 2; ++j)
#pragma unroll
        for (int ks = 0; ks < 2; ++ks)
          acc[4 + i][j] = __builtin_amdgcn_mfma_f32_16x16x32_bf16(af[i][ks], bf0[j][ks], acc[4 + i][j], 0, 0, 0);
    __builtin_amdgcn_s_setprio(0);
    asm volatile("s_waitcnt vmcnt(4)" ::: "memory");
    __builtin_amdgcn_s_barrier();
  }
#undef STG

  // ---------------- epilogue ----------------
  if (region == 0){
    if (f32out){
#pragma unroll
      for (int mi = 0; mi < 8; ++mi){
        const int row = (mi >> 2) * 128 + wr * 64 + (mi & 3) * 16 + quad * 4;
#pragma unroll
        for (int nj = 0; nj < 4; ++nj){
          const int gn = n0 + (nj >> 1) * 128 + wc * 32 + (nj & 1) * 16 + l15;
#pragma unroll
          for (int rr = 0; rr < 4; ++rr){
            const int gm = m0 + row + rr;
            oF[((size_t)gm << 12) + gn] = acc[mi][nj][rr];
          }
        }
      }
    } else {
#pragma unroll
      for (int mi = 0; mi < 8; ++mi){
        const int row = (mi >> 2) * 128 + wr * 64 + (mi & 3) * 16 + quad * 4;
#pragma unroll
        for (int nj = 0; nj < 4; ++nj){
          const int gn = n0 + (nj >> 1) * 128 + wc * 32 + (nj & 1) * 16 + l15;
#pragma unroll
          for (int rr = 0; rr < 4; ++rr){
            const int gm = m0 + row + rr;
            oQ[((size_t)gm << 12) + gn] = f2bf(acc[mi][nj][rr]);
          }
        }
      }
    }
  } else if (region == 1){
#pragma unroll
    for (int mi = 0; mi < 8; ++mi){
      const int row = (mi >> 2) * 128 + wr * 64 + (mi & 3) * 16 + quad * 4;
#pragma unroll
      for (int nj = 0; nj < 4; ++nj){
        const int gn = n0 - 4096 + (nj >> 1) * 128 + wc * 32 + (nj & 1) * 16 + l15;
#pragma unroll
        for (int rr = 0; rr < 4; ++rr){
          const int gm = m0 + row + rr;
          oK[((size_t)gm << 10) + gn] = f2bf(acc[mi][nj][rr]);
        }
      }
    }
  } else {
#pragma unroll
    for (int mi = 0; mi < 8; ++mi){
      const int gm0 = m0 + (mi >> 2) * 128 + wr * 64 + (mi & 3) * 16 + quad * 4;
      const int b = gm0 >> 11, s0 = gm0 & 2047;
#pragma unroll
      for (int nj = 0; nj < 4; ++nj){
        const int dg = n0 - 5120 + (nj >> 1) * 128 + wc * 32 + (nj & 1) * 16 + l15;
        const int kvh = dg >> 7, d = dg & 127;
        ushort4v pk;
#pragma unroll
        for (int rr = 0; rr < 4; ++rr) pk[rr] = f2bf(acc[mi][nj][rr]);
        *(ushort4v*)(oVt + (((size_t)(b * 8 + kvh) * 128 + d) * 2048 + s0)) = pk;
      }
    }
  }
}

// ---------------- RoPE apply (in-place on Q and K), sin/cos inline ----------------
// Q additionally folded with SM_SCALE*log2(e) so attention scores land in exp2 domain.
__global__ void rope_apply_k(unsigned short* __restrict__ Qb, unsigned short* __restrict__ Kb,
                             const int* __restrict__ pos){
  int t = blockIdx.x * 256 + threadIdx.x;  // 1,310,720 total
  unsigned short* base;
  int row, ch;
  bool isq = (t < 1048576);
  if (isq){ row = t >> 8; int c = t & 255; base = Qb + ((size_t)row << 12) + (c >> 3) * 128; ch = c & 7; }
  else { int t2 = t - 1048576; row = t2 >> 6; int c = t2 & 63; base = Kb + ((size_t)row << 10) + (c >> 3) * 128; ch = c & 7; }
  float p = (float)pos[row];
  const float qs = 0.08838834764831845f * 1.44269504088896340736f; // (1/sqrt(128))*log2(e)
  float sc_out = isq ? qs : 1.0f;
  int d0 = ch * 8;
  short8 x0 = *(short8*)(base + d0);
  short8 x1 = *(short8*)(base + d0 + 64);
  short8 y0, y1;
#pragma unroll
  for (int j = 0; j < 8; ++j){
    float ang = p * exp2f(-(float)(d0 + j) * 0.20762050593045952f); // log2(1e4)/64
    float sn = sinf(ang), cs = cosf(ang);
    float a  = bf2f((unsigned short)x0[j]);
    float bb = bf2f((unsigned short)x1[j]);
    y0[j] = (short)f2bf((a * cs - bb * sn) * sc_out);
    y1[j] = (short)f2bf((bb * cs + a * sn) * sc_out);
  }
  *(short8*)(base + d0)      = y0;
  *(short8*)(base + d0 + 64) = y1;
}

// ---------------- flash attention, sliding window 1024 ----------------
// Swapped-QK 32x32 structure: 4 warps x 32 q-rows = 128 rows/block.
// grid (16 qtiles, 32 heads, 2 batch); block 256 = 4 waves.
__global__ __launch_bounds__(256, 2) void flash_swa(
    const unsigned short* __restrict__ Q,
    const unsigned short* __restrict__ K,
    const unsigned short* __restrict__ Vt,
    const int* __restrict__ amask,
    unsigned short* __restrict__ attn)
{
  __shared__ __align__(16) unsigned short Kl[2][64 * 128];   // 32 KB
  __shared__ __align__(16) unsigned short Vl[2][128 * 64];   // 32 KB
  __shared__ __align__(16) unsigned int   Pl[4][1024];       // 16 KB: per-warp [q=32][kpair=32]
  const int h = blockIdx.y, b = blockIdx.z;
  const int kv = h >> 2;
  const int tid = threadIdx.x, w = tid >> 6, lane = tid & 63;
  const int l31 = lane & 31, hi = lane >> 5, hi4 = hi << 2;
  const int qb = blockIdx.x * 128;
  const int t0 = qb >> 6;                 // 64-tile index of block start
  const int qw0 = qb + w * 32;            // this warp's first q row
  const int aw = t0 + (w >> 1);           // this warp's diagonal 64-tile

  // Whole-sequence amask check (conservative): bench mask is all-ones -> fast path.
  bool anybad = false;
  {
    const int* ap = amask + b * 2048 + lane * 32;
#pragma unroll
    for (int i = 0; i < 8; ++i){
      int4 mv = *(const int4*)(ap + i * 4);
      anybad |= (mv.x <= 0) | (mv.y <= 0) | (mv.z <= 0) | (mv.w <= 0);
    }
  }
  const bool allv = (__ballot(anybad) == 0ull);

  // Q fragments (B-operand of swapped QK): lane holds col q=l31, k-slice hi*8+j
  bf16x8 qf[8];
  {
    const unsigned short* qbase = Q + (((size_t)(b * 2048 + qw0 + l31)) << 12) + h * 128;
#pragma unroll
    for (int ds = 0; ds < 8; ++ds) qf[ds] = *(const bf16x8*)(qbase + ds * 16 + hi * 8);
  }

  f32x16 acco[4];
#pragma unroll
  for (int i = 0; i < 4; ++i)
#pragma unroll
    for (int j = 0; j < 16; ++j) acco[i][j] = 0.f;
  float m_i = -1e30f, l_i = 0.f;

  const int jb0 = (t0 >= 16) ? (t0 - 16) : 0;
  const int jtend = t0 + 1;

#define STAGE_KV(JT, BUF)                                                                  \
  {                                                                                        \
    const int k0s = (JT) * 64;                                                             \
    _Pragma("unroll")                                                                      \
    for (int i_ = 0; i_ < 4; ++i_){                                                        \
      int u_ = i_ * 4 + w;                                                                 \
      int r_ = u_ * 4 + (lane >> 4);                                                       \
      int c_ = lane & 15;                                                                  \
      gl2lds16(K + (((size_t)(b * 2048 + k0s + r_)) << 10) + kv * 128 + ((c_ ^ (r_ & 15)) << 3), \
               (char*)Kl[BUF] + u_ * 1024);                                                \
    }                                                                                      \
    _Pragma("unroll")                                                                      \
    for (int i_ = 0; i_ < 4; ++i_){                                                        \
      int u_ = i_ * 4 + w;                                                                 \
      int d_ = u_ * 8 + (lane >> 3);                                                       \
      int c_ = lane & 7;                                                                   \
      gl2lds16(Vt + ((size_t)(b * 8 + kv) * 128 + d_) * 2048 + k0s + ((c_ ^ (d_ & 7)) << 3), \
               (char*)Vl[BUF] + u_ * 1024);                                                \
    }                                                                                      \
  }

  STAGE_KV(jb0, 0);
  __syncthreads();

  unsigned int* Pw = &Pl[w][0];
  int cur = 0;
  for (int jt = jb0; jt <= jtend; ++jt){
    if (jt < jtend) STAGE_KV(jt + 1, cur ^ 1);

    const bool active = (jt >= aw - 16) && (jt <= aw);
    if (active){
      const int k0 = jt * 64;
      const unsigned short* Klc = Kl[cur];
      const unsigned short* Vlc = Vl[cur];

      // ---- QK^T (swapped): ps[kb] = S^T block, rows k = kb*32 + crow, cols q ----
      f32x16 ps[2];
#pragma unroll
      for (int kb = 0; kb < 2; ++kb)
#pragma unroll
        for (int j = 0; j < 16; ++j) ps[kb][j] = 0.f;

      __builtin_amdgcn_s_setprio(1);
#pragma unroll
      for (int ds = 0; ds < 8; ++ds){
#pragma unroll
        for (int kb = 0; kb < 2; ++kb){
          int r = kb * 32 + l31;
          bf16x8 kf = *(const bf16x8*)&Klc[r * 128 + (((ds * 2 + hi) ^ (r & 15)) << 3)];
          ps[kb] = __builtin_amdgcn_mfma_f32_32x32x16_bf16(kf, qf[ds], ps[kb], 0, 0, 0);
        }
      }
      __builtin_amdgcn_s_setprio(0);

      // ---- masking: only diagonal / window-edge tiles (or masked sequences) ----
      const bool slow = (jt == aw) || (jt == aw - 16) || (!allv);
      if (slow){
        unsigned long long mb = __ballot(amask[b * 2048 + k0 + lane] > 0);
        int irow = qw0 + l31;
#pragma unroll
        for (int kb = 0; kb < 2; ++kb)
#pragma unroll
          for (int reg = 0; reg < 16; ++reg){
            int jv = k0 + kb * 32 + (reg & 3) + 8 * (reg >> 2) + hi4;
            bool valid = (jv <= irow) && (jv >= irow - 1024) &&
                         (((mb >> (jv & 63)) & 1ull) != 0ull);
            ps[kb][reg] = valid ? ps[kb][reg] : -1e30f;
          }
      }

      // ---- in-register online softmax (exp2 domain, defer-max THR=8) ----
      float t16[16];
#pragma unroll
      for (int r = 0; r < 16; ++r) t16[r] = fmaxf(ps[0][r], ps[1][r]);
      float t8[8];
#pragma unroll
      for (int r = 0; r < 8; ++r) t8[r] = fmaxf(t16[r], t16[r + 8]);
      float t4[4];
#pragma unroll
      for (int r = 0; r < 4; ++r) t4[r] = fmaxf(t8[r], t8[r + 4]);
      float vm = fmaxf(fmaxf(t4[0], t4[1]), fmaxf(t4[2], t4[3]));
      float vmax = fmaxf(vm, __shfl_xor(vm, 32));

      if (!__all(vmax - m_i <= 8.0f)){
        float mnew = fmaxf(m_i, vmax);
        float alpha = exp2f(m_i - mnew);
        m_i = mnew;
        l_i *= alpha;
#pragma unroll
        for (int db = 0; db < 4; ++db) acco[db] *= alpha;
      }

#pragma unroll
      for (int kb = 0; kb < 2; ++kb)
#pragma unroll
        for (int reg = 0; reg < 16; ++reg) ps[kb][reg] = exp2f(ps[kb][reg] - m_i);

      float s16[16];
#pragma unroll
      for (int r = 0; r < 16; ++r) s16[r] = ps[0][r] + ps[1][r];
      float s8[8];
#pragma unroll
      for (int r = 0; r < 8; ++r) s8[r] = s16[r] + s16[r + 8];
      float s4[4];
#pragma unroll
      for (int r = 0; r < 4; ++r) s4[r] = s8[r] + s8[r + 4];
      float sm = (s4[0] + s4[1]) + (s4[2] + s4[3]);
      l_i += sm + __shfl_xor(sm, 32);

      // ---- P -> LDS ([q][kpair] u32, 16B-chunk XOR swizzle), then read B-frags ----
#pragma unroll
      for (int kb = 0; kb < 2; ++kb)
#pragma unroll
        for (int g = 0; g < 4; ++g){
          unsigned p0 = (unsigned)f2bf(ps[kb][g * 4 + 0]) | ((unsigned)f2bf(ps[kb][g * 4 + 1]) << 16);
          unsigned p1 = (unsigned)f2bf(ps[kb][g * 4 + 2]) | ((unsigned)f2bf(ps[kb][g * 4 + 3]) << 16);
          int ch = (kb * 4 + g) ^ (l31 & 7);
          uint2v pv_; pv_[0] = p0; pv_[1] = p1;
          *(uint2v*)&Pw[l31 * 32 + ch * 4 + hi * 2] = pv_;
        }
      bf16x8 pa[4];
#pragma unroll
      for (int ks = 0; ks < 4; ++ks)
        pa[ks] = *(const bf16x8*)&Pw[l31 * 32 + (((ks * 2 + hi) ^ (l31 & 7)) << 2)];

      // ---- PV: acco[db] (O^T block) += mfma(V^T frag, P frag) ----
      __builtin_amdgcn_s_setprio(1);
#pragma unroll
      for (int ks = 0; ks < 4; ++ks){
#pragma unroll
        for (int db = 0; db < 4; ++db){
          int d = db * 32 + l31;
          bf16x8 vf = *(const bf16x8*)&Vlc[d * 64 + (((ks * 2 + hi) ^ (d & 7)) << 3)];
          acco[db] = __builtin_amdgcn_mfma_f32_32x32x16_bf16(vf, pa[ks], acco[db], 0, 0, 0);
        }
      }
      __builtin_amdgcn_s_setprio(0);
    }

    __syncthreads();
    cur ^= 1;
  }
#undef STAGE_KV

  // ---- epilogue: per-warp LDS transpose (reuse Kl area), coalesced stores ----
  float invl = 1.f / l_i;
  unsigned short* Ep = ((unsigned short*)Kl) + w * 4096;  // 32 q-rows x 128 d, XOR-swizzled
  {
    const int q = l31;
#pragma unroll
    for (int db = 0; db < 4; ++db)
#pragma unroll
      for (int reg = 0; reg < 16; ++reg){
        int dc = db * 4 + (reg >> 2);          // d>>3
        int dl = (reg & 3) + hi4;              // d&7
        Ep[q * 128 + ((dc ^ (q & 15)) << 3) + dl] = f2bf(acco[db][reg] * invl);
      }
  }
  {
    const int rr_ = lane >> 4, cc = lane & 15;
#pragma unroll
    for (int p8 = 0; p8 < 8; ++p8){
      int q = p8 * 4 + rr_;
      short8 vv = *(const short8*)&Ep[q * 128 + ((cc ^ (q & 15)) << 3)];
      size_t off = (((size_t)(b * 2048 + qb + w * 32 + q)) << 12) + h * 128 + cc * 8;
      *(short8*)(attn + off) = vv;
    }
  }
}

// ---------------- launch ----------------
extern "C" void kernel_launch(void* const* d_in, const int* in_sizes, int n_in,
                              void* d_out, int out_size, void* d_ws, size_t ws_size,
                              hipStream_t stream){
  const float* hidden = (const float*)d_in[0];   // [2,2048,4096] fp32
  const int* amask = (const int*)d_in[1];
  const int* pos   = (const int*)d_in[2];
  const float* qw = (const float*)d_in[3];       // [4096,4096] fp32
  const float* kw = (const float*)d_in[4];       // [4096,1024] fp32
  const float* vw = (const float*)d_in[5];       // [4096,1024] fp32
  const float* ow = (const float*)d_in[6];       // [4096,4096] fp32

  // Workspace layout — exactly 128 MiB, with liveness reuse.
  char* ws = (char*)d_ws;
  unsigned short* hb   = (unsigned short*)(ws + 0);           // hidden bf16 (32MB); dead after gemm#1 -> ot
  unsigned short* qt   = (unsigned short*)(ws + 33554432);    // q_w^T bf16 (32MB); dead after gemm#1 -> attn
  unsigned short* kt   = (unsigned short*)(ws + 67108864);    // k_w^T bf16 (8MB)
  unsigned short* vtw  = (unsigned short*)(ws + 75497472);    // v_w^T bf16 (8MB)
  unsigned short* Qb   = (unsigned short*)(ws + 83886080);    // [2,2048,32,128] (32MB)
  unsigned short* Kb   = (unsigned short*)(ws + 117440512);   // [2,2048,8,128] (8MB)
  unsigned short* Vtb  = (unsigned short*)(ws + 125829120);   // [2,8,128,2048] (8MB) -> ends at 128MiB
  unsigned short* ot   = hb;                                  // O-weight bf16^T after gemm#1
  unsigned short* attn = qt;                                  // flash output after gemm#1
  float* outp = (float*)d_out;                                // [2,2048,4096] fp32

  hipLaunchKernelGGL(conv_f32_bf16, dim3(16384), dim3(256), 0, stream, hidden, hb);
  hipLaunchKernelGGL(transpose_cvt, dim3(64, 64), dim3(256), 0, stream, qw, qt, 4096, 4096);
  hipLaunchKernelGGL(transpose_cvt, dim3(16, 64), dim3(256), 0, stream, kw, kt, 4096, 1024);
  hipLaunchKernelGGL(transpose_cvt, dim3(16, 64), dim3(256), 0, stream, vw, vtw, 4096, 1024);
  hipLaunchKernelGGL(gemm_bt, dim3(24, 16), dim3(512), 0, stream,
                     hb, qt, kt, vtw, Qb, Kb, Vtb, (float*)nullptr, 0);
  hipLaunchKernelGGL(transpose_cvt, dim3(64, 64), dim3(256), 0, stream, ow, ot, 4096, 4096); // hb dead
  hipLaunchKernelGGL(rope_apply_k, dim3(5120), dim3(256), 0, stream, Qb, Kb, pos);
  hipLaunchKernelGGL(flash_swa, dim3(16, 32, 2), dim3(256), 0, stream, Qb, Kb, Vtb, amask, attn);
  hipLaunchKernelGGL(gemm_bt, dim3(16, 16), dim3(512), 0, stream,
                     attn, ot, ot, ot, nullptr, nullptr, nullptr, outp, 1);
}